// Round 1
// baseline (159.403 us; speedup 1.0000x reference)
//
#include <hip/hip_runtime.h>
#include <stdint.h>

typedef unsigned long long u64;

// Problem constants
#define NN 32
#define CC 256
#define HH 28
#define WW 28
#define PP 784          // H*W
#define NHW 25088       // N*H*W  (per-channel BN count)
#define WPO 36          // packed words per output channel: 9 taps * 4 words
#define RT 4            // output rows per conv block

// ---------------------------------------------------------------------------
// K0: zero the stats accumulators
// ---------------------------------------------------------------------------
__global__ __launch_bounds__(256) void zero_stats(int* s1i, u64* s1q, double* s2s, double* s2q) {
    int c = threadIdx.x;
    s1i[c] = 0; s1q[c] = 0ull; s2s[c] = 0.0; s2q[c] = 0.0;
}

// ---------------------------------------------------------------------------
// K1: binarize + bit-pack x (NCHW f32) -> xp [N][P][4] u64 (bit c%64 of word c/64)
// grid (28, 32) = (h, n), block 256. Wave g packs channels g*64..g*64+63.
// ---------------------------------------------------------------------------
__global__ __launch_bounds__(256) void pack_x(const float* __restrict__ x, u64* __restrict__ xp) {
    int h = blockIdx.x, n = blockIdx.y;
    int tid = threadIdx.x, lane = tid & 63, g = tid >> 6;
    int c = tid;
    const float* px = x + (((size_t)n * CC + c) * PP) + h * WW;
    float vals[28];
#pragma unroll
    for (int k = 0; k < 7; ++k) ((float4*)vals)[k] = ((const float4*)px)[k];
    u64* dst = xp + ((size_t)n * PP + h * WW) * 4 + g;
#pragma unroll
    for (int i = 0; i < 28; ++i) {
        u64 m = __ballot(vals[i] > 0.0f);
        if (lane == 0) dst[(size_t)i * 4] = m;
    }
}

// ---------------------------------------------------------------------------
// K1b: binarize + pack weights [O][C][3][3] -> wp [O][9][4] u64
// grid 256 (= o), block 256.
// ---------------------------------------------------------------------------
__global__ __launch_bounds__(256) void pack_w(const float* __restrict__ w, u64* __restrict__ wp) {
    int o = blockIdx.x;
    int tid = threadIdx.x, lane = tid & 63, g = tid >> 6;
    int c = tid;
    const float* pw = w + ((size_t)o * CC + c) * 9;
#pragma unroll
    for (int tap = 0; tap < 9; ++tap) {
        u64 m = __ballot(pw[tap] > 0.0f);
        if (lane == 0) wp[(size_t)o * WPO + tap * 4 + g] = m;
    }
}

// ---------------------------------------------------------------------------
// K2/K5: XNOR-popcount 3x3 conv. grid (7 rowtiles, 4 oblocks, 32 n), block 256.
// Each wave: one output row (r = r0 + wid), lane = output channel within oblock.
// Weights in registers (36 u64/lane); input patch in LDS (broadcast reads).
// MODE 0: write v int16, accumulate exact int stats.
// MODE 1: write v int16, accumulate double stats of (v + residual).
// ---------------------------------------------------------------------------
template<int MODE>
__global__ __launch_bounds__(256) void binconv(
    const u64* __restrict__ xp, const u64* __restrict__ wp,
    short* __restrict__ vout, const float* __restrict__ xres,
    int* __restrict__ s_i, u64* __restrict__ s_q,
    double* __restrict__ s2s, double* __restrict__ s2q)
{
    __shared__ u64 lin[6 * 30 * 4];          // rows r0-1..r0+4, cols pad+28+pad, 4 words
    __shared__ double reds[4][64];
    __shared__ double redq[4][64];

    int tid = threadIdx.x, lane = tid & 63, wid = tid >> 6;
    int rt = blockIdx.x, ob = blockIdx.y, n = blockIdx.z;
    int r0 = rt * RT;
    int o = ob * 64 + lane;

    // weights -> registers (36 u64, 16B-aligned: 288B per o)
    u64 wreg[36];
    {
        const ulonglong2* wv = (const ulonglong2*)(wp + (size_t)o * WPO);
#pragma unroll
        for (int k = 0; k < 18; ++k) { ulonglong2 t = wv[k]; wreg[2 * k] = t.x; wreg[2 * k + 1] = t.y; }
    }

    // stage input rows r0-1 .. r0+RT into LDS (cols 1..28; 0/29 are never read)
    for (int idx = tid; idx < 6 * 56; idx += 256) {
        int row = idx / 56, off = idx % 56;      // off in 16B units (2 u64)
        int gr = r0 - 1 + row;
        if (gr >= 0 && gr < HH) {
            ulonglong2 t = *(const ulonglong2*)(xp + ((size_t)n * PP + gr * WW) * 4 + off * 2);
            *(ulonglong2*)&lin[(row * 30 + 1) * 4 + off * 2] = t;
        }
    }
    __syncthreads();

    int r = r0 + wid;                         // wave-uniform output row
    bool rup = (r > 0), rdn = (r < HH - 1);
    int nr = 1 + (int)rup + (int)rdn;

    double ts = 0.0, tq = 0.0;
    const float* resrow = (MODE == 1) ? (xres + ((size_t)n * CC + o) * PP + r * WW) : nullptr;
    short* vrow = vout + ((size_t)n * PP + (size_t)r * WW) * CC + o;

    for (int c = 0; c < WW; ++c) {
        int acc = 0;
        int nc = 3 - (c == 0) - (c == WW - 1);
#pragma unroll
        for (int dr = -1; dr <= 1; ++dr) {
            if (dr == -1 && !rup) continue;   // wave-uniform branches
            if (dr == 1 && !rdn) continue;
            int lr = wid + dr + 1;
#pragma unroll
            for (int dc = -1; dc <= 1; ++dc) {
                int cc = c + dc;
                if (cc < 0 || cc >= WW) continue;
                const u64* pp = &lin[(lr * 30 + cc + 1) * 4];
                ulonglong2 a = *(const ulonglong2*)pp;
                ulonglong2 b = *(const ulonglong2*)(pp + 2);
                const int t = ((dr + 1) * 3 + (dc + 1)) * 4;
                acc += __popcll(a.x ^ wreg[t + 0]) + __popcll(a.y ^ wreg[t + 1])
                     + __popcll(b.x ^ wreg[t + 2]) + __popcll(b.y ^ wreg[t + 3]);
            }
        }
        int dot = 64 * 4 * nr * nc - 2 * acc;   // padded taps contribute 0 (skipped)
        vrow[(size_t)c * CC] = (short)dot;
        if (MODE == 0) {
            ts += (double)dot; tq += (double)(dot * dot);
        } else {
            float t2 = (float)dot + resrow[c];
            ts += (double)t2; tq += (double)t2 * (double)t2;
        }
    }

    reds[wid][lane] = ts; redq[wid][lane] = tq;
    __syncthreads();
    if (wid == 0) {
        double S = reds[0][lane] + reds[1][lane] + reds[2][lane] + reds[3][lane];
        double Q = redq[0][lane] + redq[1][lane] + redq[2][lane] + redq[3][lane];
        if (MODE == 0) {
            atomicAdd(&s_i[o], (int)S);
            atomicAdd(&s_q[o], (u64)Q);
        } else {
            atomicAdd(&s2s[o], S);
            atomicAdd(&s2q[o], Q);
        }
    }
}

// ---------------------------------------------------------------------------
// K3: BN1 affine params from exact int stats.  sign(bn1) == (A*v + B > 0)
// ---------------------------------------------------------------------------
__global__ __launch_bounds__(256) void bnprep1(const int* __restrict__ s_i, const u64* __restrict__ s_q,
                                               const float* __restrict__ gamma, const float* __restrict__ beta,
                                               float* __restrict__ A, float* __restrict__ B) {
    int c = threadIdx.x;
    double mean = (double)s_i[c] * (1.0 / NHW);
    double msq  = (double)s_q[c] * (1.0 / NHW);
    double var  = msq - mean * mean;
    double istd = 1.0 / sqrt(var + 1e-5);
    double a = (double)gamma[c] * istd;
    A[c] = (float)a;
    B[c] = (float)((double)beta[c] - mean * a);
}

__global__ __launch_bounds__(256) void bnprep2(const double* __restrict__ ss, const double* __restrict__ sq,
                                               const float* __restrict__ gamma, const float* __restrict__ beta,
                                               float* __restrict__ SC, float* __restrict__ BI) {
    int c = threadIdx.x;
    double mean = ss[c] * (1.0 / NHW);
    double msq  = sq[c] * (1.0 / NHW);
    double var  = msq - mean * mean;
    double istd = 1.0 / sqrt(var + 1e-5);
    double a = (double)gamma[c] * istd;
    SC[c] = (float)a;
    BI[c] = (float)((double)beta[c] - mean * a);
}

// ---------------------------------------------------------------------------
// K4: sign(BN1(v1)) -> bit-pack for conv2. grid (8, 32), block 256.
// ---------------------------------------------------------------------------
__global__ __launch_bounds__(256) void repack(const short* __restrict__ v1,
                                              const float* __restrict__ A, const float* __restrict__ B,
                                              u64* __restrict__ xp2) {
    int pt = blockIdx.x, n = blockIdx.y;
    int tid = threadIdx.x, lane = tid & 63, g = tid >> 6;
    int c = g * 64 + lane;
    float a = A[c], b = B[c];
    for (int i = 0; i < 98; ++i) {
        int p = pt * 98 + i;
        int v = v1[((size_t)n * PP + p) * CC + c];
        u64 m = __ballot(fmaf(a, (float)v, b) > 0.0f);
        if (lane == 0) xp2[((size_t)n * PP + p) * 4 + g] = m;
    }
}

// ---------------------------------------------------------------------------
// K7: out = clip(SC*(v2 + x) + BI, -1, 1), NHWC int16 -> NCHW f32 via LDS transpose
// grid (4 ctiles, 13 ptiles, 32 n), block 256.
// ---------------------------------------------------------------------------
__global__ __launch_bounds__(256) void finalize(const short* __restrict__ v2, const float* __restrict__ x,
                                                const float* __restrict__ SC, const float* __restrict__ BI,
                                                float* __restrict__ out) {
    __shared__ short t[64 * 66];   // stride 66 shorts -> conflict-free column reads
    int ct = blockIdx.x, pt = blockIdx.y, n = blockIdx.z;
    int p0 = pt * 64, c0 = ct * 64;
    int tid = threadIdx.x;
    for (int idx = tid; idx < 64 * 64; idx += 256) {
        int i = idx >> 6, j = idx & 63;
        int p = p0 + i;
        if (p < PP) t[i * 66 + j] = v2[((size_t)n * PP + p) * CC + c0 + j];
    }
    __syncthreads();
    int pl = tid & 63;
    int p = p0 + pl;
    if (p < PP) {
        for (int cl = tid >> 6; cl < 64; cl += 4) {
            int c = c0 + cl;
            float val = (float)t[pl * 66 + cl] + x[((size_t)n * CC + c) * PP + p];
            float r = fmaf(SC[c], val, BI[c]);
            r = fminf(fmaxf(r, -1.0f), 1.0f);
            out[((size_t)n * CC + c) * PP + p] = r;
        }
    }
}

// ---------------------------------------------------------------------------
extern "C" void kernel_launch(void* const* d_in, const int* in_sizes, int n_in,
                              void* d_out, int out_size, void* d_ws, size_t ws_size,
                              hipStream_t stream) {
    (void)in_sizes; (void)n_in; (void)out_size; (void)ws_size;
    const float* x   = (const float*)d_in[0];
    const float* w1  = (const float*)d_in[1];
    const float* g1  = (const float*)d_in[2];
    const float* b1  = (const float*)d_in[3];
    const float* w2  = (const float*)d_in[4];
    const float* g2  = (const float*)d_in[5];
    const float* b2  = (const float*)d_in[6];
    float* out = (float*)d_out;

    char* ws = (char*)d_ws;
    u64*    xp1 = (u64*)(ws + 0);            //   802816 B
    u64*    xp2 = (u64*)(ws + 802816);       //   802816 B
    u64*    wp1 = (u64*)(ws + 1605632);      //    73728 B
    u64*    wp2 = (u64*)(ws + 1679360);      //    73728 B
    int*    s1i = (int*)(ws + 1753088);      //     1024 B
    u64*    s1q = (u64*)(ws + 1754112);      //     2048 B
    double* s2s = (double*)(ws + 1756160);   //     2048 B
    double* s2q = (double*)(ws + 1758208);   //     2048 B
    float*  bnA = (float*)(ws + 1760256);    //     1024 B
    float*  bnB = (float*)(ws + 1761280);    //     1024 B
    float*  sc2 = (float*)(ws + 1762304);    //     1024 B
    float*  bi2 = (float*)(ws + 1763328);    //     1024 B
    short*  v12 = (short*)(ws + 1764352);    // 12845056 B (v1, then reused as v2)

    zero_stats<<<1, 256, 0, stream>>>(s1i, s1q, s2s, s2q);
    pack_x<<<dim3(28, 32), 256, 0, stream>>>(x, xp1);
    pack_w<<<256, 256, 0, stream>>>(w1, wp1);
    pack_w<<<256, 256, 0, stream>>>(w2, wp2);
    binconv<0><<<dim3(7, 4, 32), 256, 0, stream>>>(xp1, wp1, v12, nullptr, s1i, s1q, nullptr, nullptr);
    bnprep1<<<1, 256, 0, stream>>>(s1i, s1q, g1, b1, bnA, bnB);
    repack<<<dim3(8, 32), 256, 0, stream>>>(v12, bnA, bnB, xp2);
    binconv<1><<<dim3(7, 4, 32), 256, 0, stream>>>(xp2, wp2, v12, x, nullptr, nullptr, s2s, s2q);
    bnprep2<<<1, 256, 0, stream>>>(s2s, s2q, g2, b2, sc2, bi2);
    finalize<<<dim3(4, 13, 32), 256, 0, stream>>>(v12, x, sc2, bi2, out);
}